// Round 9
// baseline (128.457 us; speedup 1.0000x reference)
//
#include <hip/hip_runtime.h>

#define HW (512*512)

typedef __attribute__((ext_vector_type(8))) short bfrag;   // 8 x bf16
typedef __attribute__((ext_vector_type(4))) float ffrag;   // 4 x f32 acc
typedef __attribute__((ext_vector_type(4))) float fx4;
typedef __attribute__((ext_vector_type(4))) unsigned int ux4;
typedef __attribute__((ext_vector_type(2))) unsigned int ux2;

__device__ __forceinline__ unsigned short f2bf(float f) {
  unsigned int u = __float_as_uint(f);
  u += 0x7fffu + ((u >> 16) & 1u);        // round-to-nearest-even
  return (unsigned short)(u >> 16);
}
__device__ __forceinline__ unsigned int pk2(float a, float b) {
  return (unsigned int)f2bf(a) | ((unsigned int)f2bf(b) << 16);
}
// LDS address swizzle: XOR 16B-slot bits [7:4] with bits [11:8].
// Applied identically to writes and reads; permutes within aligned 256B
// blocks -> kills the c*256B write-lane stride conflict (32-way -> ~4-way).
__device__ __forceinline__ int swz(int a) { return a ^ ((a >> 4) & 0xF0); }

// ---------- Kernel W: pack conv weights, taps folded into K ----------------
// Fragment fid = t*3 + m (t = ci8-block 0..31, m = tap-quad 0..2).
// K = 32 = 4 taps x 8 ci: k = q*8 + j -> tap = 4m+q, ci = t*8 + j.
__global__ __launch_bounds__(256) void pack_w_k(
    const float* __restrict__ cw, unsigned short* __restrict__ wp) {
  int gid = blockIdx.x * 256 + threadIdx.x;
  if (gid >= 96 * 64) return;
  int fid = gid >> 6, lane = gid & 63;
  int t = fid / 3, m = fid - t * 3;
  int q = lane >> 4, co = lane & 15;
  int tap = 4 * m + q;
  unsigned short v[8];
#pragma unroll
  for (int j = 0; j < 8; ++j) {
    int ci = t * 8 + j;
    float f = (co < 8 && tap < 9) ? cw[(co * 256 + ci) * 9 + tap] : 0.0f;
    v[j] = f2bf(f);
  }
  *(uint4*)(wp + gid * 8) = *(const uint4*)v;
}

// -------------- Fused 3x3 conv: 8-row x 128-wide strips --------------------
// 256 blocks (1/CU), 512 thr (8 waves, 1 out-row each). Per t (8 ci): stage
// 10 rows x 136 px x 8ci bf16 into swizzled dbuf LDS; 24 ds_read_b128 +
// 24 MFMA (K=32=4taps x 8ci) per wave. One barrier per t.
constexpr int RSB  = 136 * 16;      // 2176 B per LDS row
constexpr int BUFB = 10 * RSB;      // 21760 B per buffer (256B-multiple)

__global__ __launch_bounds__(512, 4) void conv_fused_k(
    const float* __restrict__ x, const unsigned short* __restrict__ wp,
    const float* __restrict__ cb, float* __restrict__ xc) {
  __shared__ __align__(16) char xs[2 * BUFB];     // 43520 B
  const int tid  = threadIdx.x;
  const int wid  = tid >> 6, lane = tid & 63;
  const int q    = lane >> 4, p = lane & 15;
  const int ro   = wid;                            // out-row within strip

  // XCD-swizzle: each XCD owns a contiguous 64-row band (8 vstrips x 4 cols)
  const int bid = blockIdx.x;
  const int xcd = bid & 7, idx = bid >> 3;
  const int vstrip = xcd * 8 + (idx & 7);
  const int col    = idx >> 3;
  const int h0 = vstrip * 8, w0 = col * 128;

  // ---- staging unit descriptors: u = (row 0..9, cc 0..33, h4 0..1) --------
  // unit1 = tid (all), unit2 = 512+tid (tid < 168)
  const int row1 = tid / 68, rem1 = tid - row1 * 68;
  const int cc1 = rem1 >> 1, h41 = rem1 & 1;
  const int gh1 = h0 - 1 + row1, gpx1 = w0 + cc1 * 4 - 4;
  const bool ok1 = ((unsigned)gh1 < 512u) && ((unsigned)gpx1 < 509u);
  const float* gp1 = x + (size_t)(h41 * 4) * HW
                   + min(max(gh1, 0), 511) * 512 + min(max(gpx1, 0), 508);
  const int wb1 = row1 * RSB + cc1 * 64 + h41 * 8;

  const int u2 = 512 + tid;
  const bool act2 = (tid < 168);
  const int row2 = u2 / 68, rem2 = u2 - row2 * 68;
  const int cc2 = rem2 >> 1, h42 = rem2 & 1;
  const int gh2 = h0 - 1 + row2, gpx2 = w0 + cc2 * 4 - 4;
  const bool ok2 = act2 && ((unsigned)gh2 < 512u) && ((unsigned)gpx2 < 509u);
  const float* gp2 = x + (size_t)(h42 * 4) * HW
                   + min(max(gh2, 0), 511) * 512 + min(max(gpx2, 0), 508);
  const int wb2 = row2 * RSB + cc2 * 64 + h42 * 8;

  // ---- per-m LDS read offsets: tap = 4m+q (clamped), dy = tap/3 -----------
  int mo[3];
#pragma unroll
  for (int m = 0; m < 3; ++m) {
    int tap = 4 * m + q; if (tap > 8) tap = 8;
    int dy = (tap * 11) >> 5;
    int dx = tap - 3 * dy;
    mo[m] = dy * RSB + dx * 16;
  }
  const int base0 = ro * RSB + (p + 3) * 16;

  fx4 S1a, S1b, S1c, S1d, S2a, S2b, S2c, S2d;

#define ISSUE(t)                                                          \
  { const float* g1_ = gp1 + (size_t)((t) * 8) * HW;                      \
    S1a = *(const fx4*)(g1_);                                             \
    S1b = *(const fx4*)(g1_ + (size_t)HW);                                \
    S1c = *(const fx4*)(g1_ + 2 * (size_t)HW);                            \
    S1d = *(const fx4*)(g1_ + 3 * (size_t)HW);                            \
    if (act2) {                                                           \
      const float* g2_ = gp2 + (size_t)((t) * 8) * HW;                    \
      S2a = *(const fx4*)(g2_);                                           \
      S2b = *(const fx4*)(g2_ + (size_t)HW);                              \
      S2c = *(const fx4*)(g2_ + 2 * (size_t)HW);                          \
      S2d = *(const fx4*)(g2_ + 3 * (size_t)HW);                          \
    } }

#define WRITE(tb_)                                                        \
  { _Pragma("unroll") for (int j_ = 0; j_ < 4; ++j_) {                    \
      ux2 v_;                                                             \
      v_.x = pk2(S1a[j_], S1b[j_]); v_.y = pk2(S1c[j_], S1d[j_]);         \
      if (!ok1) { v_.x = 0u; v_.y = 0u; }                                 \
      *(ux2*)(xs + swz((tb_) + wb1 + j_ * 16)) = v_;                      \
    }                                                                     \
    if (act2) {                                                           \
      _Pragma("unroll") for (int j_ = 0; j_ < 4; ++j_) {                  \
        ux2 v_;                                                           \
        v_.x = pk2(S2a[j_], S2b[j_]); v_.y = pk2(S2c[j_], S2d[j_]);       \
        if (!ok2) { v_.x = 0u; v_.y = 0u; }                               \
        *(ux2*)(xs + swz((tb_) + wb2 + j_ * 16)) = v_;                    \
      }                                                                   \
    } }

  ffrag acc[8];
#pragma unroll
  for (int i = 0; i < 8; ++i) acc[i] = ffrag{0.f, 0.f, 0.f, 0.f};

  ISSUE(0);
  WRITE(0);
  __syncthreads();

#pragma unroll 1
  for (int t = 0; t < 32; ++t) {
    // A fragments first (their vmcnt wait won't drain staging loads)
    const unsigned short* wpt = wp + (size_t)(t * 3) * 512 + lane * 8;
    bfrag a0 = *(const bfrag*)(wpt);
    bfrag a1 = *(const bfrag*)(wpt + 512);
    bfrag a2 = *(const bfrag*)(wpt + 1024);

    if (t < 31) ISSUE(t + 1);          // next ci-chunk flies across MFMAs

    // MFMA phase: 24 ds_read_b128 + 24 MFMA on buf[t&1]
    const int tb = (t & 1) * BUFB;
#pragma unroll
    for (int kk = 0; kk < 8; ++kk) {
      const int ab = tb + base0 + kk * 256;
      bfrag b0 = *(const bfrag*)(xs + swz(ab + mo[0]));
      acc[kk] = __builtin_amdgcn_mfma_f32_16x16x32_bf16(a0, b0, acc[kk], 0, 0, 0);
      bfrag b1 = *(const bfrag*)(xs + swz(ab + mo[1]));
      acc[kk] = __builtin_amdgcn_mfma_f32_16x16x32_bf16(a1, b1, acc[kk], 0, 0, 0);
      bfrag b2 = *(const bfrag*)(xs + swz(ab + mo[2]));
      acc[kk] = __builtin_amdgcn_mfma_f32_16x16x32_bf16(a2, b2, acc[kk], 0, 0, 0);
    }

    if (t < 31) {
      WRITE(((t + 1) & 1) * BUFB);     // dbuf: no read-drain barrier needed
      __syncthreads();                 // writes visible before t+1 reads
    }
  }
#undef ISSUE
#undef WRITE

  // epilogue: D col = lane&15 (px), row = q*4 + reg (co, 0..7 valid)
  if (lane < 32) {
    const int orow = h0 + ro;
#pragma unroll
    for (int kk = 0; kk < 8; ++kk)
#pragma unroll
      for (int reg = 0; reg < 4; ++reg) {
        int co = q * 4 + reg;
        xc[co * HW + orow * 512 + w0 + kk * 16 + p] = acc[kk][reg] + cb[co];
      }
  }
}

// ------------- Kernel B: argmax one-hot -> 8x8 mean pool -> unfold ---------
__global__ __launch_bounds__(256) void argmax_pool_unfold_k(
    const float* __restrict__ xc, float* __restrict__ U) {
  const int lane = threadIdx.x & 63;
  const int wv   = threadIdx.x >> 6;
  const int cell = blockIdx.x * 4 + wv;      // 0..4095
  const int hd = cell >> 6, wd = cell & 63;  // fm coords (64x64)
  const int h = hd * 8 + (lane >> 3), w = wd * 8 + (lane & 7);
  const int pix = h * 512 + w;

  float best = xc[pix];
  int bc = 0;
#pragma unroll
  for (int c = 1; c < 8; ++c) {
    float v = xc[c * HW + pix];
    if (v > best) { best = v; bc = c; }
  }
  float myu = 0.f;
#pragma unroll
  for (int c = 0; c < 8; ++c) {
    unsigned long long mk = __ballot(bc == c);
    if (lane == c) myu = (float)__popcll(mk) * (1.0f / 64.0f);
  }
  if (lane < 8) {
    const int k = (hd & 7) * 8 + (wd & 7);   // kernel element
    const int m = (hd >> 3) * 8 + (wd >> 3); // patch position
    U[lane * 4096 + k * 64 + m] = myu;
  }
}

// ---- Kernel C: att=(A/nz)·U, fold, 1x1 conv, out=corr*x+x, + attn copy ----
__global__ __launch_bounds__(256) void att_fold_corr_k(
    const float* __restrict__ attn, const float* __restrict__ U,
    const float* __restrict__ cw, const float* __restrict__ cb,
    float* __restrict__ out, float* __restrict__ attn_out) {
  __shared__ float Ul[2][4096];
  __shared__ float Ar[4][64];
  const int tid  = threadIdx.x;
  const int lane = tid & 63;
  const int wv   = tid >> 6;
  const int l    = blockIdx.x * 4 + wv;
  const int hq = l >> 6, wq = l & 63;
  const int h = hq * 8 + (lane >> 3), w = wq * 8 + (lane & 7);

  for (int i = tid; i < 1024; i += 256)
    ((fx4*)Ul[0])[i] = ((const fx4*)U)[i];
  __syncthreads();

  float corrv[8];
#pragma unroll 1
  for (int c = 0; c < 8; ++c) {
    if (c < 7)
      for (int i = tid; i < 1024; i += 256)
        ((fx4*)Ul[(c + 1) & 1])[i] = ((const fx4*)(U + (c + 1) * 4096))[i];

    const int aidx = ((c << 12) + l) * 64 + lane;
    float av = attn[aidx];
    attn_out[aidx] = av;                      // output 1: verbatim copy
    unsigned long long nzm = __ballot(av != 0.0f);
    float inv = 1.0f / ((float)__popcll(nzm) + 1e-5f);
    Ar[wv][lane] = av * inv;

    const float* u = Ul[c & 1];
    float s = 0.f;
#pragma unroll
    for (int k = 0; k < 64; ++k)
      s = fmaf(Ar[wv][k], u[k * 64 + lane], s);
    corrv[c] = s;
    __syncthreads();
  }

  const int pix = h * 512 + w;
#pragma unroll
  for (int d = 0; d < 8; ++d) {
    float s = cb[d];
#pragma unroll
    for (int c = 0; c < 8; ++c)
      s = fmaf(corrv[c], cw[d * 8 + c], s);
    float v = out[d * HW + pix];
    out[d * HW + pix] = fmaf(s, v, v);
  }
}

extern "C" void kernel_launch(void* const* d_in, const int* in_sizes, int n_in,
                              void* d_out, int out_size, void* d_ws, size_t ws_size,
                              hipStream_t stream) {
  const float* x    = (const float*)d_in[0];
  const float* attn = (const float*)d_in[1];
  const float* cw   = (const float*)d_in[2];
  const float* cb   = (const float*)d_in[3];
  const float* qw   = (const float*)d_in[4];
  const float* qb   = (const float*)d_in[5];
  float* out = (float*)d_out;

  char* ws = (char*)d_ws;
  unsigned short* wpack = (unsigned short*)ws;   // 96 frags * 1KB = 96 KB
  float* U = (float*)(ws + 98304);               // 128 KB
  float* xc = out;                               // x_conv lives in out[0:2M]

  pack_w_k<<<dim3(24), dim3(256), 0, stream>>>(cw, wpack);
  conv_fused_k<<<dim3(256), dim3(512), 0, stream>>>(x, wpack, cb, xc);
  argmax_pool_unfold_k<<<dim3(1024), dim3(256), 0, stream>>>(xc, U);
  att_fold_corr_k<<<dim3(1024), dim3(256), 0, stream>>>(attn, U, qw, qb,
                                                        out, out + 2097152);
}

// Round 10
// 120.122 us; speedup vs baseline: 1.0694x; 1.0694x over previous
//
#include <hip/hip_runtime.h>

#define HW (512*512)

typedef __attribute__((ext_vector_type(8))) short bfrag;   // 8 x bf16
typedef __attribute__((ext_vector_type(4))) float ffrag;   // 4 x f32 acc
typedef __attribute__((ext_vector_type(4))) float fx4;
typedef __attribute__((ext_vector_type(4))) unsigned int ux4;
typedef __attribute__((ext_vector_type(2))) unsigned int ux2;

__device__ __forceinline__ unsigned short f2bf(float f) {
  unsigned int u = __float_as_uint(f);
  u += 0x7fffu + ((u >> 16) & 1u);        // round-to-nearest-even
  return (unsigned short)(u >> 16);
}
__device__ __forceinline__ unsigned int pk2(float a, float b) {
  return (unsigned int)f2bf(a) | ((unsigned int)f2bf(b) << 16);
}
// LDS address swizzle: XOR 16B-slot bits [7:4] with bits [11:8].
__device__ __forceinline__ int swz(int a) { return a ^ ((a >> 4) & 0xF0); }

// ---------- Kernel W: pack conv weights, taps folded into K ----------------
__global__ __launch_bounds__(256) void pack_w_k(
    const float* __restrict__ cw, unsigned short* __restrict__ wp) {
  int gid = blockIdx.x * 256 + threadIdx.x;
  if (gid >= 96 * 64) return;
  int fid = gid >> 6, lane = gid & 63;
  int t = fid / 3, m = fid - t * 3;
  int q = lane >> 4, co = lane & 15;
  int tap = 4 * m + q;
  unsigned short v[8];
#pragma unroll
  for (int j = 0; j < 8; ++j) {
    int ci = t * 8 + j;
    float f = (co < 8 && tap < 9) ? cw[(co * 256 + ci) * 9 + tap] : 0.0f;
    v[j] = f2bf(f);
  }
  *(uint4*)(wp + gid * 8) = *(const uint4*)v;
}

// -------------- Fused 3x3 conv: 8-row x 128-wide strips --------------------
// 256 blocks (1/CU), 512 thr. 2-deep register prefetch (sets P/Q): loads for
// chunk t+2 issued before MFMA(t), written to LDS after MFMA(t+1) -> ~2 MFMA
// phases of latency cover; 64KB/CU in flight even across barriers.
constexpr int RSB  = 136 * 16;      // 2176 B per LDS row
constexpr int BUFB = 10 * RSB;      // 21760 B per buffer

__global__ __launch_bounds__(512, 2) void conv_fused_k(
    const float* __restrict__ x, const unsigned short* __restrict__ wp,
    const float* __restrict__ cb, float* __restrict__ xc) {
  __shared__ __align__(16) char xs[2 * BUFB];     // 43520 B
  const int tid  = threadIdx.x;
  const int wid  = tid >> 6, lane = tid & 63;
  const int q    = lane >> 4, p = lane & 15;
  const int ro   = wid;                            // out-row within strip

  // XCD-swizzle: each XCD owns a contiguous 64-row band
  const int bid = blockIdx.x;
  const int xcd = bid & 7, idx = bid >> 3;
  const int vstrip = xcd * 8 + (idx & 7);
  const int col    = idx >> 3;
  const int h0 = vstrip * 8, w0 = col * 128;

  // ---- staging unit descriptors (t-invariant) ----
  const int row1 = tid / 68, rem1 = tid - row1 * 68;
  const int cc1 = rem1 >> 1, h41 = rem1 & 1;
  const int gh1 = h0 - 1 + row1, gpx1 = w0 + cc1 * 4 - 4;
  const bool ok1 = ((unsigned)gh1 < 512u) && ((unsigned)gpx1 < 509u);
  const float* gp1 = x + (size_t)(h41 * 4) * HW
                   + min(max(gh1, 0), 511) * 512 + min(max(gpx1, 0), 508);
  const int wb1 = row1 * RSB + cc1 * 64 + h41 * 8;

  const int u2 = 512 + tid;
  const bool act2 = (tid < 168);
  const int row2 = u2 / 68, rem2 = u2 - row2 * 68;
  const int cc2 = rem2 >> 1, h42 = rem2 & 1;
  const int gh2 = h0 - 1 + row2, gpx2 = w0 + cc2 * 4 - 4;
  const bool ok2 = act2 && ((unsigned)gh2 < 512u) && ((unsigned)gpx2 < 509u);
  const float* gp2 = x + (size_t)(h42 * 4) * HW
                   + min(max(gh2, 0), 511) * 512 + min(max(gpx2, 0), 508);
  const int wb2 = row2 * RSB + cc2 * 64 + h42 * 8;

  // ---- per-m LDS read offsets ----
  int mo[3];
#pragma unroll
  for (int m = 0; m < 3; ++m) {
    int tap = 4 * m + q; if (tap > 8) tap = 8;
    int dy = (tap * 11) >> 5;
    int dx = tap - 3 * dy;
    mo[m] = dy * RSB + dx * 16;
  }
  const int base0 = ro * RSB + (p + 3) * 16;

  // two independent in-flight register sets
  fx4 P1a, P1b, P1c, P1d, P2a, P2b, P2c, P2d;
  fx4 Q1a, Q1b, Q1c, Q1d, Q2a, Q2b, Q2c, Q2d;

#define ISSUE_SET(t, R1a, R1b, R1c, R1d, R2a, R2b, R2c, R2d)              \
  { const float* g1_ = gp1 + (size_t)((t) * 8) * HW;                      \
    R1a = *(const fx4*)(g1_);                                             \
    R1b = *(const fx4*)(g1_ + (size_t)HW);                                \
    R1c = *(const fx4*)(g1_ + 2 * (size_t)HW);                            \
    R1d = *(const fx4*)(g1_ + 3 * (size_t)HW);                            \
    if (act2) {                                                           \
      const float* g2_ = gp2 + (size_t)((t) * 8) * HW;                    \
      R2a = *(const fx4*)(g2_);                                           \
      R2b = *(const fx4*)(g2_ + (size_t)HW);                              \
      R2c = *(const fx4*)(g2_ + 2 * (size_t)HW);                          \
      R2d = *(const fx4*)(g2_ + 3 * (size_t)HW);                          \
    } }

#define WRITE_SET(tb_, R1a, R1b, R1c, R1d, R2a, R2b, R2c, R2d)            \
  { _Pragma("unroll") for (int j_ = 0; j_ < 4; ++j_) {                    \
      ux2 v_;                                                             \
      v_.x = pk2(R1a[j_], R1b[j_]); v_.y = pk2(R1c[j_], R1d[j_]);         \
      if (!ok1) { v_.x = 0u; v_.y = 0u; }                                 \
      *(ux2*)(xs + swz((tb_) + wb1 + j_ * 16)) = v_;                      \
    }                                                                     \
    if (act2) {                                                           \
      _Pragma("unroll") for (int j_ = 0; j_ < 4; ++j_) {                  \
        ux2 v_;                                                           \
        v_.x = pk2(R2a[j_], R2b[j_]); v_.y = pk2(R2c[j_], R2d[j_]);       \
        if (!ok2) { v_.x = 0u; v_.y = 0u; }                               \
        *(ux2*)(xs + swz((tb_) + wb2 + j_ * 16)) = v_;                    \
      }                                                                   \
    } }

#define ISSUE_P(t) ISSUE_SET(t, P1a, P1b, P1c, P1d, P2a, P2b, P2c, P2d)
#define ISSUE_Q(t) ISSUE_SET(t, Q1a, Q1b, Q1c, Q1d, Q2a, Q2b, Q2c, Q2d)
#define WRITE_P(tb_) WRITE_SET(tb_, P1a, P1b, P1c, P1d, P2a, P2b, P2c, P2d)
#define WRITE_Q(tb_) WRITE_SET(tb_, Q1a, Q1b, Q1c, Q1d, Q2a, Q2b, Q2c, Q2d)

#define MFMA_PHASE(tb_)                                                   \
  { _Pragma("unroll") for (int kk = 0; kk < 8; ++kk) {                    \
      const int ab = (tb_) + base0 + kk * 256;                            \
      bfrag b0 = *(const bfrag*)(xs + swz(ab + mo[0]));                   \
      acc[kk] = __builtin_amdgcn_mfma_f32_16x16x32_bf16(a0, b0, acc[kk], 0, 0, 0); \
      bfrag b1 = *(const bfrag*)(xs + swz(ab + mo[1]));                   \
      acc[kk] = __builtin_amdgcn_mfma_f32_16x16x32_bf16(a1, b1, acc[kk], 0, 0, 0); \
      bfrag b2 = *(const bfrag*)(xs + swz(ab + mo[2]));                   \
      acc[kk] = __builtin_amdgcn_mfma_f32_16x16x32_bf16(a2, b2, acc[kk], 0, 0, 0); \
    } }

  ffrag acc[8];
#pragma unroll
  for (int i = 0; i < 8; ++i) acc[i] = ffrag{0.f, 0.f, 0.f, 0.f};

  // prologue: chunk0 -> buf0; chunk1 in flight in P
  ISSUE_P(0);
  WRITE_P(0);
  ISSUE_P(1);
  __syncthreads();

#pragma unroll 1
  for (int t = 0; t < 32; t += 2) {
    {   // even: MFMA chunk t (buf0); P holds t+1; issue Q(t+2)
      const unsigned short* wpt = wp + (size_t)(t * 3) * 512 + lane * 8;
      bfrag a0 = *(const bfrag*)(wpt);
      bfrag a1 = *(const bfrag*)(wpt + 512);
      bfrag a2 = *(const bfrag*)(wpt + 1024);
      if (t + 2 < 32) ISSUE_Q(t + 2);
      MFMA_PHASE(0);
      WRITE_P(BUFB);                 // chunk t+1 -> buf1
      __syncthreads();
    }
    {   // odd: MFMA chunk t+1 (buf1); Q holds t+2; issue P(t+3)
      const unsigned short* wpt = wp + (size_t)((t + 1) * 3) * 512 + lane * 8;
      bfrag a0 = *(const bfrag*)(wpt);
      bfrag a1 = *(const bfrag*)(wpt + 512);
      bfrag a2 = *(const bfrag*)(wpt + 1024);
      if (t + 3 < 32) ISSUE_P(t + 3);
      MFMA_PHASE(BUFB);
      if (t + 2 < 32) {
        WRITE_Q(0);                  // chunk t+2 -> buf0
        __syncthreads();
      }
    }
  }
#undef ISSUE_SET
#undef WRITE_SET
#undef ISSUE_P
#undef ISSUE_Q
#undef WRITE_P
#undef WRITE_Q
#undef MFMA_PHASE

  // epilogue: D col = lane&15 (px), row = q*4 + reg (co, 0..7 valid)
  if (lane < 32) {
    const int orow = h0 + ro;
#pragma unroll
    for (int kk = 0; kk < 8; ++kk)
#pragma unroll
      for (int reg = 0; reg < 4; ++reg) {
        int co = q * 4 + reg;
        xc[co * HW + orow * 512 + w0 + kk * 16 + p] = acc[kk][reg] + cb[co];
      }
  }
}

// ------------- Kernel B: argmax one-hot -> 8x8 mean pool -> unfold ---------
__global__ __launch_bounds__(256) void argmax_pool_unfold_k(
    const float* __restrict__ xc, float* __restrict__ U) {
  const int lane = threadIdx.x & 63;
  const int wv   = threadIdx.x >> 6;
  const int cell = blockIdx.x * 4 + wv;      // 0..4095
  const int hd = cell >> 6, wd = cell & 63;  // fm coords (64x64)
  const int h = hd * 8 + (lane >> 3), w = wd * 8 + (lane & 7);
  const int pix = h * 512 + w;

  float best = xc[pix];
  int bc = 0;
#pragma unroll
  for (int c = 1; c < 8; ++c) {
    float v = xc[c * HW + pix];
    if (v > best) { best = v; bc = c; }
  }
  float myu = 0.f;
#pragma unroll
  for (int c = 0; c < 8; ++c) {
    unsigned long long mk = __ballot(bc == c);
    if (lane == c) myu = (float)__popcll(mk) * (1.0f / 64.0f);
  }
  if (lane < 8) {
    const int k = (hd & 7) * 8 + (wd & 7);   // kernel element
    const int m = (hd >> 3) * 8 + (wd >> 3); // patch position
    U[lane * 4096 + k * 64 + m] = myu;
  }
}

// ---- Kernel C: att=(A/nz)·U, fold, 1x1 conv, out=corr*x+x, + attn copy ----
__global__ __launch_bounds__(256) void att_fold_corr_k(
    const float* __restrict__ attn, const float* __restrict__ U,
    const float* __restrict__ cw, const float* __restrict__ cb,
    float* __restrict__ out, float* __restrict__ attn_out) {
  __shared__ float Ul[2][4096];
  __shared__ float Ar[4][64];
  const int tid  = threadIdx.x;
  const int lane = tid & 63;
  const int wv   = tid >> 6;
  const int l    = blockIdx.x * 4 + wv;
  const int hq = l >> 6, wq = l & 63;
  const int h = hq * 8 + (lane >> 3), w = wq * 8 + (lane & 7);

  for (int i = tid; i < 1024; i += 256)
    ((fx4*)Ul[0])[i] = ((const fx4*)U)[i];
  __syncthreads();

  float corrv[8];
#pragma unroll 1
  for (int c = 0; c < 8; ++c) {
    if (c < 7)
      for (int i = tid; i < 1024; i += 256)
        ((fx4*)Ul[(c + 1) & 1])[i] = ((const fx4*)(U + (c + 1) * 4096))[i];

    const int aidx = ((c << 12) + l) * 64 + lane;
    float av = attn[aidx];
    attn_out[aidx] = av;                      // output 1: verbatim copy
    unsigned long long nzm = __ballot(av != 0.0f);
    float inv = 1.0f / ((float)__popcll(nzm) + 1e-5f);
    Ar[wv][lane] = av * inv;

    const float* u = Ul[c & 1];
    float s = 0.f;
#pragma unroll
    for (int k = 0; k < 64; ++k)
      s = fmaf(Ar[wv][k], u[k * 64 + lane], s);
    corrv[c] = s;
    __syncthreads();
  }

  const int pix = h * 512 + w;
#pragma unroll
  for (int d = 0; d < 8; ++d) {
    float s = cb[d];
#pragma unroll
    for (int c = 0; c < 8; ++c)
      s = fmaf(corrv[c], cw[d * 8 + c], s);
    float v = out[d * HW + pix];
    out[d * HW + pix] = fmaf(s, v, v);
  }
}

extern "C" void kernel_launch(void* const* d_in, const int* in_sizes, int n_in,
                              void* d_out, int out_size, void* d_ws, size_t ws_size,
                              hipStream_t stream) {
  const float* x    = (const float*)d_in[0];
  const float* attn = (const float*)d_in[1];
  const float* cw   = (const float*)d_in[2];
  const float* cb   = (const float*)d_in[3];
  const float* qw   = (const float*)d_in[4];
  const float* qb   = (const float*)d_in[5];
  float* out = (float*)d_out;

  char* ws = (char*)d_ws;
  unsigned short* wpack = (unsigned short*)ws;   // 96 frags * 1KB = 96 KB
  float* U = (float*)(ws + 98304);               // 128 KB
  float* xc = out;                               // x_conv lives in out[0:2M]

  pack_w_k<<<dim3(24), dim3(256), 0, stream>>>(cw, wpack);
  conv_fused_k<<<dim3(256), dim3(512), 0, stream>>>(x, wpack, cb, xc);
  argmax_pool_unfold_k<<<dim3(1024), dim3(256), 0, stream>>>(xc, U);
  att_fold_corr_k<<<dim3(1024), dim3(256), 0, stream>>>(attn, U, qw, qb,
                                                        out, out + 2097152);
}

// Round 11
// 102.840 us; speedup vs baseline: 1.2491x; 1.1680x over previous
//
#include <hip/hip_runtime.h>

#define HW (512*512)

typedef __attribute__((ext_vector_type(8))) short bfrag;   // 8 x bf16
typedef __attribute__((ext_vector_type(4))) float ffrag;   // 4 x f32 acc
typedef __attribute__((ext_vector_type(4))) float fx4;
typedef __attribute__((ext_vector_type(4))) unsigned int ux4;
typedef __attribute__((ext_vector_type(2))) unsigned int ux2;

__device__ __forceinline__ unsigned short f2bf(float f) {
  unsigned int u = __float_as_uint(f);
  u += 0x7fffu + ((u >> 16) & 1u);        // round-to-nearest-even
  return (unsigned short)(u >> 16);
}
__device__ __forceinline__ unsigned int pk2(float a, float b) {
  return (unsigned int)f2bf(a) | ((unsigned int)f2bf(b) << 16);
}
// LDS address swizzle: XOR 16B-slot bits [7:4] with bits [11:8].
__device__ __forceinline__ int swz(int a) { return a ^ ((a >> 4) & 0xF0); }

// ---------- Kernel W: pack conv weights, taps folded into K ----------------
__global__ __launch_bounds__(256) void pack_w_k(
    const float* __restrict__ cw, unsigned short* __restrict__ wp) {
  int gid = blockIdx.x * 256 + threadIdx.x;
  if (gid >= 96 * 64) return;
  int fid = gid >> 6, lane = gid & 63;
  int t = fid / 3, m = fid - t * 3;
  int q = lane >> 4, co = lane & 15;
  int tap = 4 * m + q;
  unsigned short v[8];
#pragma unroll
  for (int j = 0; j < 8; ++j) {
    int ci = t * 8 + j;
    float f = (co < 8 && tap < 9) ? cw[(co * 256 + ci) * 9 + tap] : 0.0f;
    v[j] = f2bf(f);
  }
  *(uint4*)(wp + gid * 8) = *(const uint4*)v;
}

// -------------- Fused 3x3 conv: 4-row x 128-wide strips, 2 blocks/CU -------
// 512 blocks, 512 thr (8 waves = 4 rows x 2 x-halves). Per t (8 ci): stage
// 6 rows x 136 px x 8ci bf16 (dup 1.59x, 544B runs). 2-deep P/Q register
// prefetch; double-buffered swizzled LDS; 1 barrier per chunk.
constexpr int RSB  = 136 * 16;      // 2176 B per LDS row
constexpr int BUFB = 6 * RSB;       // 13056 B per buffer

__global__ __launch_bounds__(512, 4) void conv_fused_k(
    const float* __restrict__ x, const unsigned short* __restrict__ wp,
    const float* __restrict__ cb, float* __restrict__ xc) {
  __shared__ __align__(16) char xs[2 * BUFB];     // 26112 B
  const int tid  = threadIdx.x;
  const int wid  = tid >> 6, lane = tid & 63;
  const int q    = lane >> 4, p = lane & 15;
  const int ro   = wid >> 1, xh = wid & 1;         // out-row, x-half

  // XCD-swizzle: each XCD owns a contiguous 64-row x 512-wide band
  const int bid = blockIdx.x;
  const int xcd = bid & 7, idx = bid >> 3;
  const int vstrip = xcd * 16 + (idx & 15);
  const int col    = idx >> 4;
  const int h0 = vstrip * 4, w0 = col * 128;

  // ---- staging unit descriptors (t-invariant): 408 units ----
  const bool act = (tid < 408);
  const int row1 = tid / 68, rem1 = tid - row1 * 68;
  const int cc1 = rem1 >> 1, h41 = rem1 & 1;
  const int gh1 = h0 - 1 + row1, gpx1 = w0 + cc1 * 4 - 4;
  const bool ok1 = act && ((unsigned)gh1 < 512u) && ((unsigned)gpx1 < 509u);
  const float* gp1 = x + (size_t)(h41 * 4) * HW
                   + min(max(gh1, 0), 511) * 512 + min(max(gpx1, 0), 508);
  const int wb1 = row1 * RSB + cc1 * 64 + h41 * 8;

  // ---- per-m LDS read offsets ----
  int mo[3];
#pragma unroll
  for (int m = 0; m < 3; ++m) {
    int tap = 4 * m + q; if (tap > 8) tap = 8;
    int dy = (tap * 11) >> 5;
    int dx = tap - 3 * dy;
    mo[m] = dy * RSB + dx * 16;
  }
  const int base0 = ro * RSB + (xh * 64 + p + 3) * 16;

  // two independent in-flight register sets
  fx4 P1a, P1b, P1c, P1d;
  fx4 Q1a, Q1b, Q1c, Q1d;

#define ISSUE_SET(t, R1a, R1b, R1c, R1d)                                  \
  { if (act) {                                                            \
      const float* g1_ = gp1 + (size_t)((t) * 8) * HW;                    \
      R1a = *(const fx4*)(g1_);                                           \
      R1b = *(const fx4*)(g1_ + (size_t)HW);                              \
      R1c = *(const fx4*)(g1_ + 2 * (size_t)HW);                          \
      R1d = *(const fx4*)(g1_ + 3 * (size_t)HW);                          \
    } }

#define WRITE_SET(tb_, R1a, R1b, R1c, R1d)                                \
  { if (act) {                                                            \
      _Pragma("unroll") for (int j_ = 0; j_ < 4; ++j_) {                  \
        ux2 v_;                                                           \
        v_.x = pk2(R1a[j_], R1b[j_]); v_.y = pk2(R1c[j_], R1d[j_]);       \
        if (!ok1) { v_.x = 0u; v_.y = 0u; }                               \
        *(ux2*)(xs + swz((tb_) + wb1 + j_ * 16)) = v_;                    \
      }                                                                   \
    } }

#define ISSUE_P(t) ISSUE_SET(t, P1a, P1b, P1c, P1d)
#define ISSUE_Q(t) ISSUE_SET(t, Q1a, Q1b, Q1c, Q1d)
#define WRITE_P(tb_) WRITE_SET(tb_, P1a, P1b, P1c, P1d)
#define WRITE_Q(tb_) WRITE_SET(tb_, Q1a, Q1b, Q1c, Q1d)

#define MFMA_PHASE(tb_)                                                   \
  { _Pragma("unroll") for (int kk = 0; kk < 4; ++kk) {                    \
      const int ab = (tb_) + base0 + kk * 256;                            \
      bfrag b0 = *(const bfrag*)(xs + swz(ab + mo[0]));                   \
      acc[kk] = __builtin_amdgcn_mfma_f32_16x16x32_bf16(a0, b0, acc[kk], 0, 0, 0); \
      bfrag b1 = *(const bfrag*)(xs + swz(ab + mo[1]));                   \
      acc[kk] = __builtin_amdgcn_mfma_f32_16x16x32_bf16(a1, b1, acc[kk], 0, 0, 0); \
      bfrag b2 = *(const bfrag*)(xs + swz(ab + mo[2]));                   \
      acc[kk] = __builtin_amdgcn_mfma_f32_16x16x32_bf16(a2, b2, acc[kk], 0, 0, 0); \
    } }

  ffrag acc[4];
#pragma unroll
  for (int i = 0; i < 4; ++i) acc[i] = ffrag{0.f, 0.f, 0.f, 0.f};

  // prologue: chunk0 -> buf0; chunk1 in flight in P
  ISSUE_P(0);
  WRITE_P(0);
  ISSUE_P(1);
  __syncthreads();

#pragma unroll 1
  for (int t = 0; t < 32; t += 2) {
    {   // even: MFMA chunk t (buf0); P holds t+1; issue Q(t+2)
      const unsigned short* wpt = wp + (size_t)(t * 3) * 512 + lane * 8;
      bfrag a0 = *(const bfrag*)(wpt);
      bfrag a1 = *(const bfrag*)(wpt + 512);
      bfrag a2 = *(const bfrag*)(wpt + 1024);
      if (t + 2 < 32) ISSUE_Q(t + 2);
      MFMA_PHASE(0);
      WRITE_P(BUFB);                 // chunk t+1 -> buf1
      __syncthreads();
    }
    {   // odd: MFMA chunk t+1 (buf1); Q holds t+2; issue P(t+3)
      const unsigned short* wpt = wp + (size_t)((t + 1) * 3) * 512 + lane * 8;
      bfrag a0 = *(const bfrag*)(wpt);
      bfrag a1 = *(const bfrag*)(wpt + 512);
      bfrag a2 = *(const bfrag*)(wpt + 1024);
      if (t + 3 < 32) ISSUE_P(t + 3);
      MFMA_PHASE(BUFB);
      if (t + 2 < 32) {
        WRITE_Q(0);                  // chunk t+2 -> buf0
        __syncthreads();
      }
    }
  }
#undef ISSUE_SET
#undef WRITE_SET
#undef ISSUE_P
#undef ISSUE_Q
#undef WRITE_P
#undef WRITE_Q
#undef MFMA_PHASE

  // epilogue: D col = lane&15 (px), row = q*4 + reg (co, 0..7 valid)
  if (lane < 32) {
    const int orow = h0 + ro;
    const int opx  = w0 + xh * 64 + p;
#pragma unroll
    for (int kk = 0; kk < 4; ++kk)
#pragma unroll
      for (int reg = 0; reg < 4; ++reg) {
        int co = q * 4 + reg;
        xc[co * HW + orow * 512 + opx + kk * 16] = acc[kk][reg] + cb[co];
      }
  }
}

// ------------- Kernel B: argmax one-hot -> 8x8 mean pool -> unfold ---------
__global__ __launch_bounds__(256) void argmax_pool_unfold_k(
    const float* __restrict__ xc, float* __restrict__ U) {
  const int lane = threadIdx.x & 63;
  const int wv   = threadIdx.x >> 6;
  const int cell = blockIdx.x * 4 + wv;      // 0..4095
  const int hd = cell >> 6, wd = cell & 63;  // fm coords (64x64)
  const int h = hd * 8 + (lane >> 3), w = wd * 8 + (lane & 7);
  const int pix = h * 512 + w;

  float best = xc[pix];
  int bc = 0;
#pragma unroll
  for (int c = 1; c < 8; ++c) {
    float v = xc[c * HW + pix];
    if (v > best) { best = v; bc = c; }
  }
  float myu = 0.f;
#pragma unroll
  for (int c = 0; c < 8; ++c) {
    unsigned long long mk = __ballot(bc == c);
    if (lane == c) myu = (float)__popcll(mk) * (1.0f / 64.0f);
  }
  if (lane < 8) {
    const int k = (hd & 7) * 8 + (wd & 7);   // kernel element
    const int m = (hd >> 3) * 8 + (wd >> 3); // patch position
    U[lane * 4096 + k * 64 + m] = myu;
  }
}

// ---- Kernel C: att=(A/nz)·U, fold, 1x1 conv, out=corr*x+x, + attn copy ----
__global__ __launch_bounds__(256) void att_fold_corr_k(
    const float* __restrict__ attn, const float* __restrict__ U,
    const float* __restrict__ cw, const float* __restrict__ cb,
    float* __restrict__ out, float* __restrict__ attn_out) {
  __shared__ float Ul[2][4096];
  __shared__ float Ar[4][64];
  const int tid  = threadIdx.x;
  const int lane = tid & 63;
  const int wv   = tid >> 6;
  const int l    = blockIdx.x * 4 + wv;
  const int hq = l >> 6, wq = l & 63;
  const int h = hq * 8 + (lane >> 3), w = wq * 8 + (lane & 7);

  for (int i = tid; i < 1024; i += 256)
    ((fx4*)Ul[0])[i] = ((const fx4*)U)[i];
  __syncthreads();

  float corrv[8];
#pragma unroll 1
  for (int c = 0; c < 8; ++c) {
    if (c < 7)
      for (int i = tid; i < 1024; i += 256)
        ((fx4*)Ul[(c + 1) & 1])[i] = ((const fx4*)(U + (c + 1) * 4096))[i];

    const int aidx = ((c << 12) + l) * 64 + lane;
    float av = attn[aidx];
    attn_out[aidx] = av;                      // output 1: verbatim copy
    unsigned long long nzm = __ballot(av != 0.0f);
    float inv = 1.0f / ((float)__popcll(nzm) + 1e-5f);
    Ar[wv][lane] = av * inv;

    const float* u = Ul[c & 1];
    float s = 0.f;
#pragma unroll
    for (int k = 0; k < 64; ++k)
      s = fmaf(Ar[wv][k], u[k * 64 + lane], s);
    corrv[c] = s;
    __syncthreads();
  }

  const int pix = h * 512 + w;
#pragma unroll
  for (int d = 0; d < 8; ++d) {
    float s = cb[d];
#pragma unroll
    for (int c = 0; c < 8; ++c)
      s = fmaf(corrv[c], cw[d * 8 + c], s);
    float v = out[d * HW + pix];
    out[d * HW + pix] = fmaf(s, v, v);
  }
}

extern "C" void kernel_launch(void* const* d_in, const int* in_sizes, int n_in,
                              void* d_out, int out_size, void* d_ws, size_t ws_size,
                              hipStream_t stream) {
  const float* x    = (const float*)d_in[0];
  const float* attn = (const float*)d_in[1];
  const float* cw   = (const float*)d_in[2];
  const float* cb   = (const float*)d_in[3];
  const float* qw   = (const float*)d_in[4];
  const float* qb   = (const float*)d_in[5];
  float* out = (float*)d_out;

  char* ws = (char*)d_ws;
  unsigned short* wpack = (unsigned short*)ws;   // 96 frags * 1KB = 96 KB
  float* U = (float*)(ws + 98304);               // 128 KB
  float* xc = out;                               // x_conv lives in out[0:2M]

  pack_w_k<<<dim3(24), dim3(256), 0, stream>>>(cw, wpack);
  conv_fused_k<<<dim3(512), dim3(512), 0, stream>>>(x, wpack, cb, xc);
  argmax_pool_unfold_k<<<dim3(1024), dim3(256), 0, stream>>>(xc, U);
  att_fold_corr_k<<<dim3(1024), dim3(256), 0, stream>>>(attn, U, qw, qb,
                                                        out, out + 2097152);
}